// Round 1
// baseline (50.376 us; speedup 1.0000x reference)
//
#include <hip/hip_runtime.h>
#include <math.h>

#define H 4096
#define IN 4

__device__ __forceinline__ float sigmoidf_(float x) {
    return 1.0f / (1.0f + __expf(-x));
}

// Kernel 1: gates = W_ih@x + b_ih + W_hh@h + b_hh ; then c_new/h_new.
// One block per output element j (H blocks). 4 waves: wave g computes the
// dot of W_hh row (g*H + j) with h (4096 elements, float4 loads, wave-wide).
__global__ __launch_bounds__(256) void lstm_step_kernel(
    const float* __restrict__ x,      // [4]
    const float* __restrict__ h,      // [H]
    const float* __restrict__ c,      // [H]
    const float* __restrict__ W_ih,   // [4H, 4]
    const float* __restrict__ W_hh,   // [4H, H]
    const float* __restrict__ b_ih,   // [4H]
    const float* __restrict__ b_hh,   // [4H]
    float* __restrict__ out)          // [0..4) y, [4..4+H) h_new, [4+H..4+2H) c_new
{
    const int j    = blockIdx.x;           // 0..H-1
    const int wave = threadIdx.x >> 6;     // 0..3 (gate index: i,f,g,o)
    const int lane = threadIdx.x & 63;
    const int row  = wave * H + j;

    const float4* __restrict__ Wrow = (const float4*)(W_hh + (size_t)row * H);
    const float4* __restrict__ hv   = (const float4*)h;

    float acc = 0.0f;
#pragma unroll
    for (int it = 0; it < 16; ++it) {
        const int idx = lane + it * 64;    // 0..1023 float4's
        float4 w4 = Wrow[idx];
        float4 h4 = hv[idx];
        acc += w4.x * h4.x + w4.y * h4.y + w4.z * h4.z + w4.w * h4.w;
    }
    // wave-wide (64-lane) reduction
#pragma unroll
    for (int off = 32; off > 0; off >>= 1)
        acc += __shfl_down(acc, off, 64);

    __shared__ float gate[4];
    if (lane == 0) {
        float g = acc + b_ih[row] + b_hh[row];
        const float4 wi = ((const float4*)W_ih)[row];  // row of 4
        g += wi.x * x[0] + wi.y * x[1] + wi.z * x[2] + wi.w * x[3];
        gate[wave] = g;
    }
    __syncthreads();
    if (threadIdx.x == 0) {
        const float gi = gate[0], gf = gate[1], gg = gate[2], go = gate[3];
        const float cn = sigmoidf_(gf) * c[j] + sigmoidf_(gi) * tanhf(gg);
        const float hn = sigmoidf_(go) * tanhf(cn);
        out[4 + j]     = hn;
        out[4 + H + j] = cn;
    }
}

// Kernel 2: MLP head. Single block, 12 waves (768 threads).
// wave w: y1[w] = relu(w1[w] . h_new + b1[w]); then tiny tail layers.
__global__ __launch_bounds__(768) void mlp_head_kernel(
    const float* __restrict__ w1, const float* __restrict__ b1,  // [12,H],[12]
    const float* __restrict__ w2, const float* __restrict__ b2,  // [8,12],[8]
    const float* __restrict__ w3, const float* __restrict__ b3,  // [4,8],[4]
    float* __restrict__ out)
{
    const float* __restrict__ h_new = out + 4;
    const int wave = threadIdx.x >> 6;  // 0..11
    const int lane = threadIdx.x & 63;

    __shared__ float s1[12];
    __shared__ float s2[8];

    const float4* __restrict__ wr = (const float4*)(w1 + (size_t)wave * H);
    const float4* __restrict__ hv = (const float4*)h_new;
    float acc = 0.0f;
#pragma unroll
    for (int it = 0; it < 16; ++it) {
        const int idx = lane + it * 64;
        float4 a = wr[idx];
        float4 b = hv[idx];
        acc += a.x * b.x + a.y * b.y + a.z * b.z + a.w * b.w;
    }
#pragma unroll
    for (int off = 32; off > 0; off >>= 1)
        acc += __shfl_down(acc, off, 64);
    if (lane == 0) s1[wave] = fmaxf(acc + b1[wave], 0.0f);
    __syncthreads();

    if (threadIdx.x < 8) {
        float a = b2[threadIdx.x];
#pragma unroll
        for (int k = 0; k < 12; ++k) a += w2[threadIdx.x * 12 + k] * s1[k];
        s2[threadIdx.x] = fmaxf(a, 0.0f);
    }
    __syncthreads();

    if (threadIdx.x < 4) {
        float a = b3[threadIdx.x];
#pragma unroll
        for (int k = 0; k < 8; ++k) a += w3[threadIdx.x * 8 + k] * s2[k];
        out[threadIdx.x] = a;
    }
}

extern "C" void kernel_launch(void* const* d_in, const int* in_sizes, int n_in,
                              void* d_out, int out_size, void* d_ws, size_t ws_size,
                              hipStream_t stream) {
    const float* x    = (const float*)d_in[0];
    const float* h    = (const float*)d_in[1];
    const float* c    = (const float*)d_in[2];
    const float* W_ih = (const float*)d_in[3];
    const float* W_hh = (const float*)d_in[4];
    const float* b_ih = (const float*)d_in[5];
    const float* b_hh = (const float*)d_in[6];
    const float* w1   = (const float*)d_in[7];
    const float* b1   = (const float*)d_in[8];
    const float* w2   = (const float*)d_in[9];
    const float* b2   = (const float*)d_in[10];
    const float* w3   = (const float*)d_in[11];
    const float* b3   = (const float*)d_in[12];
    float* out = (float*)d_out;

    lstm_step_kernel<<<H, 256, 0, stream>>>(x, h, c, W_ih, W_hh, b_ih, b_hh, out);
    mlp_head_kernel<<<1, 768, 0, stream>>>(w1, b1, w2, b2, w3, b3, out);
}